// Round 7
// baseline (212.639 us; speedup 1.0000x reference)
//
#include <hip/hip_runtime.h>
#include <hip/hip_bf16.h>
#include <stdint.h>

// out[b, f, t] = mask(f < jc[e]*6) * ( sum_d X[t,b,d] * W[e,d,f] + bias[e,f] ),  e = object_types[b]
// Per-sample GEMM: M=768, N=196 (pad 208), K=1024, bf16 MFMA, f32 accum.
// BM=128 x full-N 208, BK=32, 4 waves (2M x 2N). Early-out for fully-masked M-tiles.
// B(X) staged f32 via global_load_lds (source-swizzled, linear LDS dest), converted to
// bf16 at the LDS->frag read. A(W) reg-staged (transpose) into a 96B-pitch bf16 tile.
// Double-buffered LDS, one barrier per K-step, vmcnt drained AFTER compute (latency hidden).

#define NFRAMES 196
#define TPAD    208
#define BSZ     128
#define DLAT    1024
#define FIN     768
#define BM      128
#define BK      32
#define KSTEPS  (DLAT / BK)    // 32
#define MTILES  (FIN / BM)     // 6
#define NBLK    (MTILES * BSZ) // 768
#define NTHREADS 256
#define A_PITCH 48             // shorts per A row = 96B: 16B-aligned, reads+writes at bank floor

typedef short bf16x8 __attribute__((ext_vector_type(8)));
typedef float f32x4  __attribute__((ext_vector_type(4)));
typedef unsigned int u32x2 __attribute__((ext_vector_type(2)));
typedef unsigned int u32x4 __attribute__((ext_vector_type(4)));

__device__ __forceinline__ unsigned int pkbf(float lo, float hi) {
    unsigned short a = (unsigned short)__builtin_bit_cast(short, __float2bfloat16(lo));  // RNE
    unsigned short b = (unsigned short)__builtin_bit_cast(short, __float2bfloat16(hi));
    return (unsigned int)a | ((unsigned int)b << 16);
}

// async global->LDS, 16B/lane; LDS dest = wave-uniform base + lane*16 (linear).
__device__ __forceinline__ void gload16(const float* g, float* lds) {
    __builtin_amdgcn_global_load_lds(
        (const __attribute__((address_space(1))) void*)g,
        (__attribute__((address_space(3))) void*)lds,
        16, 0, 0);
}

#define VMDRAIN() asm volatile("s_waitcnt vmcnt(0)" ::: "memory")
#define BAR() do { asm volatile("s_waitcnt lgkmcnt(0)" ::: "memory"); \
                   __builtin_amdgcn_s_barrier(); } while (0)

template<int NF>
__device__ __forceinline__ void compute_step(const short* __restrict__ Ab,
                                             const float* __restrict__ Bb,
                                             const int* idxA, const int* ibase,
                                             int c0, int c1, f32x4 (&acc)[4][7]) {
    bf16x8 af[4];
    #pragma unroll
    for (int f = 0; f < 4; ++f)
        af[f] = *reinterpret_cast<const bf16x8*>(&Ab[idxA[f]]);
    #pragma unroll
    for (int nf = 0; nf < NF; ++nf) {
        f32x4 q0 = *reinterpret_cast<const f32x4*>(&Bb[ibase[nf] + c0]);
        f32x4 q1 = *reinterpret_cast<const f32x4*>(&Bb[ibase[nf] + c1]);
        u32x4 u = { pkbf(q0[0], q0[1]), pkbf(q0[2], q0[3]),
                    pkbf(q1[0], q1[1]), pkbf(q1[2], q1[3]) };
        bf16x8 bv = __builtin_bit_cast(bf16x8, u);
        #pragma unroll
        for (int f = 0; f < 4; ++f)
            acc[f][nf] = __builtin_amdgcn_mfma_f32_16x16x32_bf16(af[f], bv, acc[f][nf], 0, 0, 0);
    }
}

template<int NF>
__device__ __forceinline__ void epilogue(const f32x4 (&acc)[4][7], float* __restrict__ outB,
                                         const float* __restrict__ biasE, int fcb, int m0,
                                         int wr, int wc, int g, int lr) {
    #pragma unroll
    for (int f = 0; f < 4; ++f) {
        #pragma unroll
        for (int rr = 0; rr < 4; ++rr) {
            const int fcol = m0 + wr * 64 + f * 16 + g * 4 + rr;   // C row = (lane>>4)*4 + reg
            const float bb = biasE[fcol];
            const bool  val = fcol < fcb;
            #pragma unroll
            for (int nf = 0; nf < NF; ++nf) {
                const int t = wc * 112 + nf * 16 + lr;             // C col = lane&15
                if (t < NFRAMES)
                    outB[fcol * NFRAMES + t] = val ? (acc[f][nf][rr] + bb) : 0.f;
            }
        }
    }
}

__global__ __launch_bounds__(NTHREADS, 2)
void fused_expert_gemm(const float* __restrict__ X,      // (196,128,1024)
                       const int*   __restrict__ otypes, // (128)
                       const float* __restrict__ W,      // (16,1024,768)
                       const float* __restrict__ Bias,   // (16,768)
                       const int*   __restrict__ jc,     // (16)
                       float*       __restrict__ out)    // (128,768,196)
{
    __shared__ __align__(16) float Bsf[2][TPAD * BK];      // f32 X tile, 128B rows, 2x26.6KB
    __shared__ __align__(16) short As[2][BM * A_PITCH];    // bf16 W^T tile, 96B pitch, 2x12KB

    // XCD chunk mapping (R1, fastest): 96 consecutive logical (=16 samples) per XCD,
    // the 6 M-tiles of one sample adjacent -> concurrent -> X L2 reuse.
    const int hw      = blockIdx.x;
    const int logical = (hw & 7) * (NBLK / 8) + (hw >> 3);
    const int b       = logical / MTILES;
    const int mt      = logical - b * MTILES;
    const int m0      = mt * BM;

    const int tid = threadIdx.x;
    const int e   = otypes[b];
    const int fcb = jc[e] * 6;
    float* outB = out + (size_t)b * (FIN * NFRAMES);

    if (m0 >= fcb) {   // fully masked tile: zero-fill, skip GEMM + W fetch
        f32x4 zz = {0.f, 0.f, 0.f, 0.f};
        f32x4* dst = reinterpret_cast<f32x4*>(outB + m0 * NFRAMES);
        const int total = (BM * NFRAMES) / 4;
        for (int i = tid; i < total; i += NTHREADS) dst[i] = zz;
        return;
    }

    const int wave = tid >> 6;
    const int lane = tid & 63;
    const int lr   = lane & 15;
    const int g    = lane >> 4;
    const int wr   = wave >> 1;   // M half (64 rows)
    const int wc   = wave & 1;    // N part: 0 -> t<112 (7 frags), 1 -> t 112..207 (6 frags)

    // ---- B (X) gload setup: instr j = wave + 4*i covers rows j*8..j*8+7, lane l -> row j*8+(l>>3),
    //      chunk (l&7)^(l>>3) of the 128B row (XOR involution; LDS dest linear). ----
    const int chunk = (lane & 7) ^ (lane >> 3);
    const float* gbase[7];
    #pragma unroll
    for (int i = 0; i < 7; ++i) {
        const int j = wave + 4 * i;
        int n = j * 8 + (lane >> 3);
        int t = n < NFRAMES ? n : NFRAMES - 1;   // pad rows: clamp (outputs masked)
        gbase[i] = X + (size_t)t * (BSZ * DLAT) + (size_t)b * DLAT + chunk * 4;
    }

    // ---- A (W) reg staging: thread owns 4k x 4m micro-block; kbe rotation spreads banks ----
    const int mb  = tid & 31;
    const int kb  = tid >> 5;
    const int kbe = (kb + (mb >> 2)) & 7;
    const f32x4* __restrict__ Wv = reinterpret_cast<const f32x4*>(W);
    f32x4 wa[4];

    // LDS read indices
    int idxA[4], ibase[7];
    #pragma unroll
    for (int f = 0; f < 4; ++f)
        idxA[f] = (wr * 64 + f * 16 + lr) * A_PITCH + g * 8;     // shorts
    #pragma unroll
    for (int nf = 0; nf < 7; ++nf)
        ibase[nf] = (wc * 112 + nf * 16 + lr) * BK;              // floats
    const int c0 = ((2 * g) ^ (lr & 7)) * 4;                      // swizzled chunk offsets (floats)
    const int c1 = c0 ^ 4;

    f32x4 acc[4][7];
    #pragma unroll
    for (int f = 0; f < 4; ++f)
        #pragma unroll
        for (int nf = 0; nf < 7; ++nf) acc[f][nf] = {0.f, 0.f, 0.f, 0.f};

    auto load_W = [&](int kk) {
        #pragma unroll
        for (int i = 0; i < 4; ++i)
            wa[i] = Wv[(e * DLAT + kk + kbe * 4 + i) * (FIN / 4) + (m0 >> 2) + mb];
    };
    auto write_A = [&](int buf) {
        #pragma unroll
        for (int jj = 0; jj < 4; ++jj) {
            const int r = (mb + jj) & 3;    // rotate row order within quad
            u32x2 v = { pkbf(wa[0][r], wa[1][r]), pkbf(wa[2][r], wa[3][r]) };
            *reinterpret_cast<u32x2*>(&As[buf][(mb * 4 + r) * A_PITCH + kbe * 4]) = v;
        }
    };
    auto stage_B = [&](int buf, int koff) {   // koff in floats (tile*32)
        #pragma unroll
        for (int i = 0; i < 6; ++i)
            gload16(gbase[i] + koff, &Bsf[buf][(wave + 4 * i) * 256]);
        if (wave < 2)
            gload16(gbase[6] + koff, &Bsf[buf][(wave + 24) * 256]);
    };

    // Prologue: tile0 staged+drained; W(1) prefetched into regs.
    load_W(0);
    write_A(0);
    stage_B(0, 0);
    load_W(BK);
    VMDRAIN();
    BAR();

    // Main loop: stage k+1 (A write + B gloads) -> prefetch W(k+2) -> compute k from LDS
    // -> drain (loads had the whole compute phase to land) -> one barrier.
    #pragma unroll 1
    for (int ks = 0; ks < KSTEPS; ++ks) {
        const int buf = ks & 1;
        if (ks + 1 < KSTEPS) { write_A(buf ^ 1); stage_B(buf ^ 1, (ks + 1) * BK); }
        if (ks + 2 < KSTEPS) load_W((ks + 2) * BK);

        if (wc == 0) compute_step<7>(As[buf], Bsf[buf], idxA, ibase, c0, c1, acc);
        else         compute_step<6>(As[buf], Bsf[buf], idxA, ibase, c0, c1, acc);

        VMDRAIN();
        BAR();
    }

    const float* biasE = Bias + e * FIN;
    if (wc == 0) epilogue<7>(acc, outB, biasE, fcb, m0, wr, wc, g, lr);
    else         epilogue<6>(acc, outB, biasE, fcb, m0, wr, wc, g, lr);
}

extern "C" void kernel_launch(void* const* d_in, const int* in_sizes, int n_in,
                              void* d_out, int out_size, void* d_ws, size_t ws_size,
                              hipStream_t stream) {
    const float* X    = (const float*)d_in[0];
    const int*   ot   = (const int*)d_in[1];
    const float* W    = (const float*)d_in[2];
    const float* Bias = (const float*)d_in[3];
    const int*   jc   = (const int*)d_in[4];
    float*       out  = (float*)d_out;

    dim3 grid(NBLK);
    dim3 block(NTHREADS);
    hipLaunchKernelGGL(fused_expert_gemm, grid, block, 0, stream,
                       X, ot, W, Bias, jc, out);
}

// Round 8
// 197.874 us; speedup vs baseline: 1.0746x; 1.0746x over previous
//
#include <hip/hip_runtime.h>
#include <hip/hip_bf16.h>
#include <stdint.h>

// out[b, f, t] = mask(f < jc[e]*6) * ( sum_d X[t,b,d] * W[e,d,f] + bias[e,f] ),  e = object_types[b]
// Per-sample GEMM: M=768, N=196, K=1024, bf16 MFMA, f32 accum.
// OCCUPANCY-FIRST layout: N split in two half-blocks (t 0..111 / 112..195) ->
// grid 1536, acc[4][4]=64 regs/wave -> 3 waves/SIMD (vs 2), ~12 heavy waves/CU.
// BM=128, BK=32, 4 waves (2M x 2N). Early-out for fully-masked M-tiles.
// R1-proven loop skeleton: single LDS buffer, two non-draining barriers/K-step,
// 1-step register prefetch of W and X.

#define NFRAMES 196
#define BSZ     128
#define DLAT    1024
#define FIN     768
#define BM      128
#define BK      32
#define KSTEPS  (DLAT / BK)    // 32
#define MTILES  (FIN / BM)     // 6
#define NBLK    (2 * MTILES * BSZ) // 1536 (pairs of N-halves)
#define NTHREADS 256
#define BROWS   112            // B tile rows allocated (nh0: 112 used, nh1: 96)

typedef short bf16x8 __attribute__((ext_vector_type(8)));
typedef float f32x4  __attribute__((ext_vector_type(4)));
typedef unsigned int u32x2 __attribute__((ext_vector_type(2)));
typedef unsigned int u32x4 __attribute__((ext_vector_type(4)));

__device__ __forceinline__ unsigned int pkbf(float lo, float hi) {
    unsigned short a = (unsigned short)__builtin_bit_cast(short, __float2bfloat16(lo));  // RNE
    unsigned short b = (unsigned short)__builtin_bit_cast(short, __float2bfloat16(hi));
    return (unsigned int)a | ((unsigned int)b << 16);
}

// barrier that does NOT drain vmcnt (prefetch global loads stay in flight)
#define BAR() do { asm volatile("s_waitcnt lgkmcnt(0)" ::: "memory"); \
                   __builtin_amdgcn_s_barrier(); } while (0)

template<int NF>
__device__ __forceinline__ void compute_step(const short* __restrict__ Ab,
                                             const short* __restrict__ Bb,
                                             const int* idxA, const int* idxB,
                                             f32x4 (&acc)[4][4]) {
    bf16x8 af[4];
    #pragma unroll
    for (int f = 0; f < 4; ++f)
        af[f] = *reinterpret_cast<const bf16x8*>(&Ab[idxA[f]]);
    #pragma unroll
    for (int nf = 0; nf < NF; ++nf) {
        bf16x8 bv = *reinterpret_cast<const bf16x8*>(&Bb[idxB[nf]]);
        #pragma unroll
        for (int f = 0; f < 4; ++f)
            acc[f][nf] = __builtin_amdgcn_mfma_f32_16x16x32_bf16(af[f], bv, acc[f][nf], 0, 0, 0);
    }
}

template<int NF>
__device__ __forceinline__ void epilogue(const f32x4 (&acc)[4][4], float* __restrict__ outB,
                                         const float* __restrict__ biasE, int fcb, int m0,
                                         int t0w, int wr, int g, int lr) {
    #pragma unroll
    for (int f = 0; f < 4; ++f) {
        #pragma unroll
        for (int rr = 0; rr < 4; ++rr) {
            const int fcol = m0 + wr * 64 + f * 16 + g * 4 + rr;   // C row = (lane>>4)*4 + reg
            const float bb = biasE[fcol];
            const bool  val = fcol < fcb;
            #pragma unroll
            for (int nf = 0; nf < NF; ++nf) {
                const int t = t0w + nf * 16 + lr;                  // C col = lane&15
                if (t < NFRAMES)
                    outB[fcol * NFRAMES + t] = val ? (acc[f][nf][rr] + bb) : 0.f;
            }
        }
    }
}

template<int NV4>   // f32x4s per row (28 for 112 cols, 21 for 84 cols)
__device__ __forceinline__ void fillz(float* __restrict__ base, int tid) {
    const f32x4 zz = {0.f, 0.f, 0.f, 0.f};
    const int total = BM * NV4;
    for (int i = tid; i < total; i += NTHREADS) {
        const int r = i / NV4;
        const int c = i - r * NV4;
        *reinterpret_cast<f32x4*>(base + r * NFRAMES + c * 4) = zz;
    }
}

__global__ __launch_bounds__(NTHREADS, 3)
void fused_expert_gemm(const float* __restrict__ X,      // (196,128,1024)
                       const int*   __restrict__ otypes, // (128)
                       const float* __restrict__ W,      // (16,1024,768)
                       const float* __restrict__ Bias,   // (16,768)
                       const int*   __restrict__ jc,     // (16)
                       float*       __restrict__ out)    // (128,768,196)
{
    __shared__ short As[BM * BK];      // [m][k] bf16, 64B rows (8 KB)
    __shared__ short Bs[BROWS * BK];   // [t_local][k] bf16 (7 KB)

    // XCD chunking: 192 consecutive logicals per XCD = 16 samples; the two N-halves
    // of the same (b, mt) are adjacent (nh = bit0) so they co-run and share W in L2.
    const int hw      = blockIdx.x;
    const int logical = (hw & 7) * (NBLK / 8) + (hw >> 3);
    const int nh      = logical & 1;
    const int l2      = logical >> 1;      // 0..767
    const int b       = l2 / MTILES;
    const int mt      = l2 - b * MTILES;
    const int m0      = mt * BM;

    const int tid = threadIdx.x;
    const int e   = otypes[b];
    const int fcb = jc[e] * 6;
    float* outB = out + (size_t)b * (FIN * NFRAMES);

    const int t0   = nh * 112;             // first frame of this half
    const int RMAX = nh ? 96 : 112;        // B tile rows staged (incl. pad)

    if (m0 >= fcb) {   // fully masked tile: zero-fill this half's cols, skip GEMM
        float* base = outB + (size_t)m0 * NFRAMES + t0;
        if (nh == 0) fillz<28>(base, tid);
        else         fillz<21>(base, tid);
        return;
    }

    const int wave = tid >> 6;
    const int lane = tid & 63;
    const int lr   = lane & 15;
    const int g    = lane >> 4;
    const int wr   = wave >> 1;            // M half (64 rows)
    const int wc   = wave & 1;             // N sub-part within the half
    const int r0   = wc * (nh ? 48 : 64);  // wave's first local B row
    const bool nf4 = (nh == 0) && (wc == 0);   // 4 frags, else 3
    const int t0w  = t0 + r0;

    // A staging: thread owns 4k x 4m micro-block; kbe rotation spreads write banks
    const int mb  = tid & 31;
    const int kb  = tid >> 5;
    const int kbe = (kb + (mb >> 2)) & 7;
    // B staging: 4 threads per row, 32B (8 floats -> 8 bf16) each; 2 passes
    const int ko = tid & 3;
    const int rw = tid >> 2;
    const bool p1act = (64 + rw) < RMAX;

    const f32x4* __restrict__ Xv = reinterpret_cast<const f32x4*>(X);
    const f32x4* __restrict__ Wv = reinterpret_cast<const f32x4*>(W);

    f32x4 wa[4];      // W prefetch (4 k-rows x 4 m)
    f32x4 xb[2][2];   // X prefetch (2 passes x 8 floats)

    // Global X row per pass (clamp pad rows; their outputs are never stored)
    int trow[2];
    {
        int n0 = rw, n1 = 64 + rw;
        int tg0 = t0 + n0, tg1 = t0 + n1;
        trow[0] = tg0 < NFRAMES ? tg0 : NFRAMES - 1;
        trow[1] = tg1 < NFRAMES ? tg1 : NFRAMES - 1;
    }

    int idxA[4], idxB[4];
    #pragma unroll
    for (int f = 0; f < 4; ++f)
        idxA[f] = (wr * 64 + f * 16 + lr) * BK + g * 8;
    #pragma unroll
    for (int nf = 0; nf < 4; ++nf)
        idxB[nf] = (r0 + nf * 16 + lr) * BK + g * 8;   // nf==3 only used when nf4

    f32x4 acc[4][4];
    #pragma unroll
    for (int f = 0; f < 4; ++f)
        #pragma unroll
        for (int nf = 0; nf < 4; ++nf) acc[f][nf] = {0.f, 0.f, 0.f, 0.f};

    auto load_stage = [&](int kk) {
        #pragma unroll
        for (int i = 0; i < 4; ++i)
            wa[i] = Wv[(e * DLAT + kk + kbe * 4 + i) * (FIN / 4) + (m0 >> 2) + mb];
        {
            const int base0 = (trow[0] * BSZ + b) * (DLAT / 4) + (kk >> 2) + ko * 2;
            xb[0][0] = Xv[base0];
            xb[0][1] = Xv[base0 + 1];
        }
        if (p1act) {
            const int base1 = (trow[1] * BSZ + b) * (DLAT / 4) + (kk >> 2) + ko * 2;
            xb[1][0] = Xv[base1];
            xb[1][1] = Xv[base1 + 1];
        }
    };

    auto write_stage = [&]() {
        #pragma unroll
        for (int jj = 0; jj < 4; ++jj) {
            const int r = (mb + jj) & 3;    // rotate row order within quad
            u32x2 v = { pkbf(wa[0][r], wa[1][r]), pkbf(wa[2][r], wa[3][r]) };
            *reinterpret_cast<u32x2*>(&As[(mb * 4 + r) * BK + kbe * 4]) = v;
        }
        {
            u32x4 v = { pkbf(xb[0][0][0], xb[0][0][1]), pkbf(xb[0][0][2], xb[0][0][3]),
                        pkbf(xb[0][1][0], xb[0][1][1]), pkbf(xb[0][1][2], xb[0][1][3]) };
            *reinterpret_cast<u32x4*>(&Bs[rw * BK + ko * 8]) = v;
        }
        if (p1act) {
            u32x4 v = { pkbf(xb[1][0][0], xb[1][0][1]), pkbf(xb[1][0][2], xb[1][0][3]),
                        pkbf(xb[1][1][0], xb[1][1][1]), pkbf(xb[1][1][2], xb[1][1][3]) };
            *reinterpret_cast<u32x4*>(&Bs[(64 + rw) * BK + ko * 8]) = v;
        }
    };

    load_stage(0);

    // R1-proven skeleton: single buffer, two non-draining barriers per K-step;
    // next tile's global loads issued right after LDS writes, in flight across BAR.
    #pragma unroll 1
    for (int ks = 0; ks < KSTEPS; ++ks) {
        BAR();                 // prior iter's frag reads complete
        write_stage();         // regs -> LDS (vmcnt waits via reg deps)
        if (ks + 1 < KSTEPS)
            load_stage((ks + 1) * BK);
        BAR();                 // LDS writes visible

        if (nf4) compute_step<4>(As, Bs, idxA, idxB, acc);
        else     compute_step<3>(As, Bs, idxA, idxB, acc);
    }

    const float* biasE = Bias + e * FIN;
    if (nf4) epilogue<4>(acc, outB, biasE, fcb, m0, t0w, wr, g, lr);
    else     epilogue<3>(acc, outB, biasE, fcb, m0, t0w, wr, g, lr);
}

extern "C" void kernel_launch(void* const* d_in, const int* in_sizes, int n_in,
                              void* d_out, int out_size, void* d_ws, size_t ws_size,
                              hipStream_t stream) {
    const float* X    = (const float*)d_in[0];
    const int*   ot   = (const int*)d_in[1];
    const float* W    = (const float*)d_in[2];
    const float* Bias = (const float*)d_in[3];
    const int*   jc   = (const int*)d_in[4];
    float*       out  = (float*)d_out;

    dim3 grid(NBLK);      // 1536 = 128 samples x 6 M-tiles x 2 N-halves
    dim3 block(NTHREADS);
    hipLaunchKernelGGL(fused_expert_gemm, grid, block, 0, stream,
                       X, ot, W, Bias, jc, out);
}